// Round 17
// baseline (122.315 us; speedup 1.0000x reference)
//
#include <hip/hip_runtime.h>
#include <hip/hip_bf16.h>

typedef _Float16 f16;
typedef _Float16 f16x4 __attribute__((ext_vector_type(4)));
typedef _Float16 f16x8 __attribute__((ext_vector_type(8)));
typedef float f32x4 __attribute__((ext_vector_type(4)));

#define MFMA(a, b, c) __builtin_amdgcn_mfma_f32_16x16x32_f16((a), (b), (c), 0, 0, 0)

#define BB 4
#define NPOS 32768
#define HH 4
#define NBLK 1024          // k1 blocks of 128 positions
#define NBLK3 4096         // k3 blocks of 32 positions (1 wave)
#define STATB 2304         // t[32][32] f16 (2048 B) + s[32][4] f16 (256 B)
#define LDP 136            // padded f16 row stride for EV (272 B)

__device__ __forceinline__ f16x8 ldx8(const float* p) {
  float4 a = *(const float4*)p;
  float4 b = *(const float4*)(p + 4);
  return (f16x8){(f16)a.x, (f16)a.y, (f16)a.z, (f16)a.w,
                 (f16)b.x, (f16)b.y, (f16)b.z, (f16)b.w};
}

// ---------------------------------------------------------------------------
// k0: weight prep, fragment-major (chunk*512 f16 + lane*8 = contiguous 1 KB
// per wave-fragment).
//   wkvF chunk = (h*4+nt)*4+ks ; lane l: n = 16nt+(l&15), c = 32ks+8(l>>4)+j
//   wqF  chunk = (h*2+a)*4+ks  ; lane l: n = SIGMA(a, l&15), c = 32ks+8(l>>4)+j
//     SIGMA places feature d' = 8*(i>>2)+4a+(i&3) at A-row i, so the q-logit
//     MFMA output lands with lane (lg,ln) holding d = 8lg+4a+r = the exact
//     fragment k-slots for the y-MFMA (j = 4a+r).
// ---------------------------------------------------------------------------
__global__ __launch_bounds__(256)
void la_k0_prep(const float* __restrict__ wqkv, f16* __restrict__ wkvF,
                f16* __restrict__ wqF) {
  const int g0 = blockIdx.x * 256 + threadIdx.x;  // 16384 threads
  for (int i = g0; i < 32768; i += 16384) {
    int j = i & 7, l = (i >> 3) & 63, ks = (i >> 9) & 3, nt = (i >> 11) & 3,
        h = i >> 13;
    int n = 16 * nt + (l & 15);
    int c = 32 * ks + 8 * (l >> 4) + j;
    int col = (n < 32) ? (128 + h * 32 + n) : (256 + h * 32 + (n - 32));
    wkvF[i] = (f16)wqkv[c * 384 + col];
  }
  {
    int i = g0;  // 16384 elements, one per thread
    int j = i & 7, l = (i >> 3) & 63, ks = (i >> 9) & 3, a = (i >> 11) & 1,
        h = i >> 12;
    int row = l & 15;
    int n = 8 * (row >> 2) + 4 * a + (row & 3);  // SIGMA permutation
    int c = 32 * ks + 8 * (l >> 4) + j;
    wqF[i] = (f16)wqkv[c * 384 + h * 32 + n];
  }
}

// ---------------------------------------------------------------------------
// k1: per 128-pos block: k,v logits + q-logits (reusing the same xf
// fragments), e = exp(k) (m=0, exact), partial t = E.V^T via MFMA,
// q-softmax -> Qhat fragment-major to global.
// SINGLE EV buffer (17.4 KB -> 8 blocks/CU, 32 waves/CU), 2 barriers/head;
// TLP (8 waves/SIMD) supplies the latency hiding instead of the acc dbuf.
// ---------------------------------------------------------------------------
__global__ __launch_bounds__(256, 8)
void la_k1_stats(const float* __restrict__ x, const f16* __restrict__ wkvF,
                 const f16* __restrict__ wqF, char* __restrict__ stats,
                 f16* __restrict__ Qhat) {
  const int blk = blockIdx.x, t = threadIdx.x;
  const int w = t >> 6, l = t & 63, lg = l >> 4, ln = l & 15;

  __shared__ __align__(16) f16 EV[64 * LDP];  // E rows 0-31, V rows 32-63

  const float* xb = x + (size_t)blk * (128 * 128);
  f16x8 xf[2][4];
#pragma unroll
  for (int mi = 0; mi < 2; ++mi)
#pragma unroll
    for (int ks = 0; ks < 4; ++ks)
      xf[mi][ks] = ldx8(xb + (32 * w + 16 * mi + ln) * 128 + 32 * ks + 8 * lg);

  const f32x4 Z4 = {0.f, 0.f, 0.f, 0.f};

#pragma unroll 1
  for (int h = 0; h < HH; ++h) {
    // ---- kv logits ----
    f32x4 acc[2][4];
#pragma unroll
    for (int mi = 0; mi < 2; ++mi)
#pragma unroll
      for (int nt = 0; nt < 4; ++nt) acc[mi][nt] = Z4;
#pragma unroll
    for (int ks = 0; ks < 4; ++ks) {
#pragma unroll
      for (int nt = 0; nt < 4; ++nt) {
        f16x8 bf = *(const f16x8*)(wkvF + (((h * 4 + nt) * 4 + ks) << 9) + l * 8);
        acc[0][nt] = MFMA(xf[0][ks], bf, acc[0][nt]);
        acc[1][nt] = MFMA(xf[1][ks], bf, acc[1][nt]);
      }
    }

    // ---- exp + EV store + s stats ----
    {
      float sl[2] = {0.f, 0.f};
#pragma unroll
      for (int nt = 0; nt < 2; ++nt)
#pragma unroll
        for (int mi = 0; mi < 2; ++mi) {
          float e0 = __expf(acc[mi][nt][0]);
          float e1 = __expf(acc[mi][nt][1]);
          float e2 = __expf(acc[mi][nt][2]);
          float e3 = __expf(acc[mi][nt][3]);
          sl[nt] += (e0 + e1) + (e2 + e3);
          *(f16x4*)&EV[(16 * nt + ln) * LDP + 32 * w + 16 * mi + 4 * lg] =
              (f16x4){(f16)e0, (f16)e1, (f16)e2, (f16)e3};
          f32x4 vv = acc[mi][nt + 2];
          *(f16x4*)&EV[(32 + 16 * nt + ln) * LDP + 32 * w + 16 * mi + 4 * lg] =
              (f16x4){(f16)vv[0], (f16)vv[1], (f16)vv[2], (f16)vv[3]};
        }
#pragma unroll
      for (int nt = 0; nt < 2; ++nt) {
        sl[nt] += __shfl_xor(sl[nt], 16);
        sl[nt] += __shfl_xor(sl[nt], 32);
      }
      f16* sp = (f16*)(stats + (size_t)(blk * HH + h) * STATB + 2048);
      if (lg == 0) {
        sp[ln * 4 + w] = (f16)sl[0];
        sp[(16 + ln) * 4 + w] = (f16)sl[1];
      }
    }

    __syncthreads();  // EV writes visible to all waves

    // ---- t-MFMA (reads EV) + t store ----
    {
      const int tm = w >> 1, tn = w & 1;
      f32x4 tacc = Z4;
#pragma unroll
      for (int ks = 0; ks < 4; ++ks) {
        f16x8 ea = *(const f16x8*)&EV[(16 * tm + ln) * LDP + 32 * ks + 8 * lg];
        f16x8 vb = *(const f16x8*)&EV[(32 + 16 * tn + ln) * LDP + 32 * ks + 8 * lg];
        tacc = MFMA(ea, vb, tacc);
      }
      f16* tp = (f16*)(stats + (size_t)(blk * HH + h) * STATB);
#pragma unroll
      for (int r = 0; r < 4; ++r)
        tp[(16 * tm + 4 * lg + r) * 32 + 16 * tn + ln] = (f16)tacc[r];
    }

    // ---- q logits (xf as B operand; no EV access) + softmax -> Qhat ----
    {
      f32x4 qa[2][2];
#pragma unroll
      for (int mi = 0; mi < 2; ++mi)
#pragma unroll
        for (int a = 0; a < 2; ++a) qa[mi][a] = Z4;
#pragma unroll
      for (int ks = 0; ks < 4; ++ks) {
        f16x8 a0 = *(const f16x8*)(wqF + (((h * 2 + 0) * 4 + ks) << 9) + l * 8);
        f16x8 a1 = *(const f16x8*)(wqF + (((h * 2 + 1) * 4 + ks) << 9) + l * 8);
#pragma unroll
        for (int mi = 0; mi < 2; ++mi) {
          qa[mi][0] = MFMA(a0, xf[mi][ks], qa[mi][0]);
          qa[mi][1] = MFMA(a1, xf[mi][ks], qa[mi][1]);
        }
      }
#pragma unroll
      for (int mi = 0; mi < 2; ++mi) {
        float s = 0.f;
#pragma unroll
        for (int a = 0; a < 2; ++a)
#pragma unroll
          for (int r = 0; r < 4; ++r) {
            qa[mi][a][r] = __expf(qa[mi][a][r]);
            s += qa[mi][a][r];
          }
        s += __shfl_xor(s, 16);
        s += __shfl_xor(s, 32);
        const float inv = 0.17677669529663688f / s;  // 32^-0.5 / sum
        f16x8 af = (f16x8){(f16)(qa[mi][0][0] * inv), (f16)(qa[mi][0][1] * inv),
                           (f16)(qa[mi][0][2] * inv), (f16)(qa[mi][0][3] * inv),
                           (f16)(qa[mi][1][0] * inv), (f16)(qa[mi][1][1] * inv),
                           (f16)(qa[mi][1][2] * inv), (f16)(qa[mi][1][3] * inv)};
        f16* qp = Qhat + (((size_t)(blk * 8 + 2 * w + mi) * 4 + h) << 9) + l * 8;
        *(f16x8*)qp = af;
      }
    }

    __syncthreads();  // all EV reads done before next head's writes
  }
}

// ---------------------------------------------------------------------------
// k2: block per (b,h,d): plain sum of 256 chunk stats -> ctxN[bh][d][e] f16
// ---------------------------------------------------------------------------
__global__ __launch_bounds__(256)
void la_k2_combine(const char* __restrict__ stats, f16* __restrict__ ctxN) {
  const int gid = blockIdx.x;  // bh*32 + d
  const int bh = gid >> 5, d = gid & 31;
  const int b = bh >> 2, h = bh & 3;
  const int t = threadIdx.x, w = t >> 6, l = t & 63;
  const int c = t & 31, grp = t >> 5;
  __shared__ float redt[4][32];
  __shared__ float reds[4];

  float sg = 0.f, tc = 0.f;
  for (int i = grp; i < 256; i += 8) {
    const char* ub = stats + (size_t)((b * 256 + i) * HH + h) * STATB;
    tc += (float)((const f16*)ub)[d * 32 + c];
    f16x4 s4 = *(const f16x4*)(ub + 2048 + d * 8);
    sg += ((float)s4[0] + (float)s4[1]) + ((float)s4[2] + (float)s4[3]);
  }
  tc += __shfl_xor(tc, 32);
  sg += __shfl_xor(sg, 32);
  if (l < 32) redt[w][l] = tc;
  if (l == 0) reds[w] = sg;
  __syncthreads();
  if (t < 32) {
    float tt = (redt[0][t] + redt[1][t]) + (redt[2][t] + redt[3][t]);
    float ss = (reds[0] + reds[1]) + (reds[2] + reds[3]);
    ctxN[((size_t)bh * 32 + d) * 32 + t] = (f16)(tt / ss);
  }
}

// ---------------------------------------------------------------------------
// k2b: GT fold, written FRAGMENT-MAJOR to global (wout fp32 read direct):
//   GTF chunk h*8+mt, lane l', elem j holds GT(c = 16mt+(l'&15), d = 8(l'>>4)+j)
// ---------------------------------------------------------------------------
__global__ __launch_bounds__(256)
void la_k2b_fold(const f16* __restrict__ ctxN, const float* __restrict__ wout,
                 f16* __restrict__ GTF) {
  const int b = blockIdx.x, t = threadIdx.x;
  const int h = t >> 6, l = t & 63, lg = l >> 4, ln = l & 15;
  const f32x4 Z4 = {0.f, 0.f, 0.f, 0.f};

  const f16* cb = ctxN + (size_t)((b * HH + h) * 32) * 32;
  f16x8 bfrag[2];
#pragma unroll
  for (int nt = 0; nt < 2; ++nt)
    bfrag[nt] = *(const f16x8*)(cb + (16 * nt + ln) * 32 + 8 * lg);

  f16* gf = GTF + (size_t)b * 16384;
#pragma unroll
  for (int mt = 0; mt < 8; ++mt) {
    f16x8 af;  // wout rows c=16mt+ln, k = hid 32h+8lg+j  (fp32 direct)
#pragma unroll
    for (int j = 0; j < 8; ++j)
      af[j] = (f16)wout[(32 * h + 8 * lg + j) * 128 + 16 * mt + ln];
#pragma unroll
    for (int nt = 0; nt < 2; ++nt) {
      f32x4 acc = MFMA(af, bfrag[nt], Z4);
      // lane holds GT(c = 16mt+4lg+r, d = 16nt+ln); scatter to frag-major
#pragma unroll
      for (int r = 0; r < 4; ++r) {
        int dsub = 16 * nt + ln;
        gf[((h * 8 + mt) << 9) + (16 * (dsub >> 3) + 4 * lg + r) * 8 + (dsub & 7)] =
            (f16)acc[r];
      }
    }
  }
}

// ---------------------------------------------------------------------------
// k3: LEAN stream kernel — one wave per 32 positions (grid 4096): load 8
// prepacked Qhat fragments + 32 GTF fragments, 64 MFMA (transposed y:
// row=c, col=pos), LN (2 shuffles), f32x4 stores. No x read, no softmax,
// no LDS, no barriers.
// ---------------------------------------------------------------------------
__global__ __launch_bounds__(64)
void la_k3_out(const f16* __restrict__ Qhat, const f16* __restrict__ GTF,
               const float* __restrict__ bout, const float* __restrict__ lns,
               const float* __restrict__ lnb, float* __restrict__ out) {
  const int blk = blockIdx.x;
  const int l = threadIdx.x, lg = l >> 4, ln = l & 15;
  const int b = blk >> 10;              // 1024 blocks per batch (32 pos each)

  const f32x4 Z4 = {0.f, 0.f, 0.f, 0.f};
  const f16* gf = GTF + (size_t)b * 16384;

  // Qhat fragments for both 16-pos groups x 4 heads (independent loads)
  f16x8 af[2][4];
#pragma unroll
  for (int g = 0; g < 2; ++g)
#pragma unroll
    for (int h = 0; h < HH; ++h)
      af[g][h] = *(const f16x8*)(Qhat +
          (((size_t)(blk * 2 + g) * 4 + h) << 9) + l * 8);

  // yT[g][nc]: rows c = 16nc+4lg+r, col pos = blk*32+16g+ln
  f32x4 y[2][8];
#pragma unroll
  for (int g = 0; g < 2; ++g)
#pragma unroll
    for (int nc = 0; nc < 8; ++nc) y[g][nc] = Z4;

#pragma unroll
  for (int h = 0; h < HH; ++h) {
#pragma unroll
    for (int nc = 0; nc < 8; ++nc) {
      f16x8 gfr = *(const f16x8*)(gf + (((h * 8 + nc) << 9) + l * 8));
      y[0][nc] = MFMA(gfr, af[0][h], y[0][nc]);
      y[1][nc] = MFMA(gfr, af[1][h], y[1][nc]);
    }
  }

  // bias — vectorized f32x4 over c
#pragma unroll
  for (int nc = 0; nc < 8; ++nc) {
    f32x4 bb = *(const f32x4*)(bout + 16 * nc + 4 * lg);
    y[0][nc] += bb;
    y[1][nc] += bb;
  }

  // LayerNorm per pos (col=ln): reduce over c = (nc, lg, r): 32 in-lane + 2 shfl
#pragma unroll
  for (int g = 0; g < 2; ++g) {
    float s = 0.f;
#pragma unroll
    for (int nc = 0; nc < 8; ++nc)
      s += (y[g][nc][0] + y[g][nc][1]) + (y[g][nc][2] + y[g][nc][3]);
    s += __shfl_xor(s, 16);
    s += __shfl_xor(s, 32);
    const float mean = s * (1.f / 128.f);
    float v = 0.f;
#pragma unroll
    for (int nc = 0; nc < 8; ++nc)
#pragma unroll
      for (int r = 0; r < 4; ++r) {
        float dv = y[g][nc][r] - mean;
        v = fmaf(dv, dv, v);
      }
    v += __shfl_xor(v, 16);
    v += __shfl_xor(v, 32);
    const float inv = rsqrtf(v * (1.f / 128.f) + 1e-6f);

    float* op = out + (size_t)(blk * 32 + 16 * g + ln) * 128;
#pragma unroll
    for (int nc = 0; nc < 8; ++nc) {
      f32x4 sv = *(const f32x4*)(lns + 16 * nc + 4 * lg);
      f32x4 b2 = *(const f32x4*)(lnb + 16 * nc + 4 * lg);
      f32x4 o4;
#pragma unroll
      for (int r = 0; r < 4; ++r)
        o4[r] = (y[g][nc][r] - mean) * inv * sv[r] + b2[r];
      *(f32x4*)(op + 16 * nc + 4 * lg) = o4;
    }
  }
}

// ---------------------------------------------------------------------------
extern "C" void kernel_launch(void* const* d_in, const int* in_sizes, int n_in,
                              void* d_out, int out_size, void* d_ws, size_t ws_size,
                              hipStream_t stream) {
  const float* x = (const float*)d_in[0];
  const float* w_qkv = (const float*)d_in[1];
  const float* w_out = (const float*)d_in[2];
  const float* b_out = (const float*)d_in[3];
  const float* ln_s = (const float*)d_in[4];
  const float* ln_b = (const float*)d_in[5];
  float* out = (float*)d_out;

  char* ws = (char*)d_ws;
  char* stats = ws;                                   // 9437184 B
  f16* wkvF = (f16*)(ws + 9437184);                   // 65536 B
  f16* wqF = (f16*)(ws + 9437184 + 65536);            // 32768 B
  f16* GTF = (f16*)(ws + 9437184 + 65536 + 32768);    // 131072 B
  f16* ctxN = (f16*)(ws + 9437184 + 65536 + 32768 + 131072);  // 32768 B
  f16* Qhat = (f16*)(ws + 9437184 + 65536 + 32768 + 131072 + 32768);  // 33554432 B

  la_k0_prep<<<dim3(64), 256, 0, stream>>>(w_qkv, wkvF, wqF);
  la_k1_stats<<<dim3(NBLK), 256, 0, stream>>>(x, wkvF, wqF, stats, Qhat);
  la_k2_combine<<<dim3(512), 256, 0, stream>>>(stats, ctxN);
  la_k2b_fold<<<dim3(BB), 256, 0, stream>>>(ctxN, w_out, GTF);
  la_k3_out<<<dim3(NBLK3), 64, 0, stream>>>(Qhat, GTF, b_out, ln_s, ln_b, out);
}

// Round 18
// 77.441 us; speedup vs baseline: 1.5795x; 1.5795x over previous
//
#include <hip/hip_runtime.h>
#include <hip/hip_bf16.h>

typedef _Float16 f16;
typedef _Float16 f16x4 __attribute__((ext_vector_type(4)));
typedef _Float16 f16x8 __attribute__((ext_vector_type(8)));
typedef float f32x4 __attribute__((ext_vector_type(4)));

#define MFMA(a, b, c) __builtin_amdgcn_mfma_f32_16x16x32_f16((a), (b), (c), 0, 0, 0)

#define BB 4
#define NPOS 32768
#define HH 4
#define NBLK 1024          // k1 blocks of 128 positions
#define NBLK3 4096         // k3 blocks of 32 positions (1 wave)
#define STATB 2304         // t[32][32] f16 (2048 B) + s[32][4] f16 (256 B)
#define LDP 136            // padded f16 row stride for EV (272 B)

__device__ __forceinline__ f16x8 ldx8(const float* p) {
  float4 a = *(const float4*)p;
  float4 b = *(const float4*)(p + 4);
  return (f16x8){(f16)a.x, (f16)a.y, (f16)a.z, (f16)a.w,
                 (f16)b.x, (f16)b.y, (f16)b.z, (f16)b.w};
}

// ---------------------------------------------------------------------------
// k0: weight prep, fragment-major (chunk*512 f16 + lane*8 = contiguous 1 KB
// per wave-fragment).
//   wkvF chunk = (h*4+nt)*4+ks ; lane l: n = 16nt+(l&15), c = 32ks+8(l>>4)+j
//   wqF  chunk = (h*2+a)*4+ks  ; lane l: n = SIGMA(a, l&15), c = 32ks+8(l>>4)+j
//     SIGMA places feature d' = 8*(i>>2)+4a+(i&3) at A-row i, so the q-logit
//     MFMA output lands with lane (lg,ln) holding d = 8lg+4a+r = the exact
//     fragment k-slots for the y-MFMA (j = 4a+r).
// ---------------------------------------------------------------------------
__global__ __launch_bounds__(256)
void la_k0_prep(const float* __restrict__ wqkv, f16* __restrict__ wkvF,
                f16* __restrict__ wqF) {
  const int g0 = blockIdx.x * 256 + threadIdx.x;  // 16384 threads
  for (int i = g0; i < 32768; i += 16384) {
    int j = i & 7, l = (i >> 3) & 63, ks = (i >> 9) & 3, nt = (i >> 11) & 3,
        h = i >> 13;
    int n = 16 * nt + (l & 15);
    int c = 32 * ks + 8 * (l >> 4) + j;
    int col = (n < 32) ? (128 + h * 32 + n) : (256 + h * 32 + (n - 32));
    wkvF[i] = (f16)wqkv[c * 384 + col];
  }
  {
    int i = g0;  // 16384 elements, one per thread
    int j = i & 7, l = (i >> 3) & 63, ks = (i >> 9) & 3, a = (i >> 11) & 1,
        h = i >> 12;
    int row = l & 15;
    int n = 8 * (row >> 2) + 4 * a + (row & 3);  // SIGMA permutation
    int c = 32 * ks + 8 * (l >> 4) + j;
    wqF[i] = (f16)wqkv[c * 384 + h * 32 + n];
  }
}

// ---------------------------------------------------------------------------
// k1: per 128-pos block: k,v logits + Q-LOGITS (reusing the same xf
// fragments — A and B lane layouts are identical), e = exp(k) (m=0, exact),
// partial t = E.V^T via MFMA, q-softmax -> Qhat fragment-major to global.
// 1 barrier/head (dbuf EV). R15 structure + s_setprio around MFMA clusters.
// ---------------------------------------------------------------------------
__global__ __launch_bounds__(256, 4)
void la_k1_stats(const float* __restrict__ x, const f16* __restrict__ wkvF,
                 const f16* __restrict__ wqF, char* __restrict__ stats,
                 f16* __restrict__ Qhat) {
  const int blk = blockIdx.x, t = threadIdx.x;
  const int w = t >> 6, l = t & 63, lg = l >> 4, ln = l & 15;

  __shared__ __align__(16) f16 EV[2][64 * LDP];  // E rows 0-31, V rows 32-63

  const float* xb = x + (size_t)blk * (128 * 128);
  f16x8 xf[2][4];
#pragma unroll
  for (int mi = 0; mi < 2; ++mi)
#pragma unroll
    for (int ks = 0; ks < 4; ++ks)
      xf[mi][ks] = ldx8(xb + (32 * w + 16 * mi + ln) * 128 + 32 * ks + 8 * lg);

  const f32x4 Z4 = {0.f, 0.f, 0.f, 0.f};

  auto logits = [&](int h, f32x4 (&acc)[2][4]) {
#pragma unroll
    for (int mi = 0; mi < 2; ++mi)
#pragma unroll
      for (int nt = 0; nt < 4; ++nt) acc[mi][nt] = Z4;
    __builtin_amdgcn_s_setprio(1);
#pragma unroll
    for (int ks = 0; ks < 4; ++ks) {
#pragma unroll
      for (int nt = 0; nt < 4; ++nt) {
        f16x8 bf = *(const f16x8*)(wkvF + (((h * 4 + nt) * 4 + ks) << 9) + l * 8);
        acc[0][nt] = MFMA(xf[0][ks], bf, acc[0][nt]);
        acc[1][nt] = MFMA(xf[1][ks], bf, acc[1][nt]);
      }
    }
    __builtin_amdgcn_s_setprio(0);
  };

  // swapped q-logits: qT[d][pos] with xf as the B operand (col = pos)
  auto qlog = [&](int h, f32x4 (&qa)[2][2]) {
#pragma unroll
    for (int mi = 0; mi < 2; ++mi)
#pragma unroll
      for (int a = 0; a < 2; ++a) qa[mi][a] = Z4;
    __builtin_amdgcn_s_setprio(1);
#pragma unroll
    for (int ks = 0; ks < 4; ++ks) {
      f16x8 a0 = *(const f16x8*)(wqF + (((h * 2 + 0) * 4 + ks) << 9) + l * 8);
      f16x8 a1 = *(const f16x8*)(wqF + (((h * 2 + 1) * 4 + ks) << 9) + l * 8);
#pragma unroll
      for (int mi = 0; mi < 2; ++mi) {
        qa[mi][0] = MFMA(a0, xf[mi][ks], qa[mi][0]);
        qa[mi][1] = MFMA(a1, xf[mi][ks], qa[mi][1]);
      }
    }
    __builtin_amdgcn_s_setprio(0);
  };

  // q softmax (m=0) + in-register af pack + Qhat store (wave-contig 1 KB)
  auto qfin = [&](int h, f32x4 (&qa)[2][2]) {
#pragma unroll
    for (int mi = 0; mi < 2; ++mi) {
      float s = 0.f;
#pragma unroll
      for (int a = 0; a < 2; ++a)
#pragma unroll
        for (int r = 0; r < 4; ++r) {
          qa[mi][a][r] = __expf(qa[mi][a][r]);
          s += qa[mi][a][r];
        }
      s += __shfl_xor(s, 16);
      s += __shfl_xor(s, 32);
      const float inv = 0.17677669529663688f / s;  // 32^-0.5 / sum
      f16x8 af = (f16x8){(f16)(qa[mi][0][0] * inv), (f16)(qa[mi][0][1] * inv),
                         (f16)(qa[mi][0][2] * inv), (f16)(qa[mi][0][3] * inv),
                         (f16)(qa[mi][1][0] * inv), (f16)(qa[mi][1][1] * inv),
                         (f16)(qa[mi][1][2] * inv), (f16)(qa[mi][1][3] * inv)};
      f16* qp = Qhat + (((size_t)(blk * 8 + 2 * w + mi) * 4 + h) << 9) + l * 8;
      *(f16x8*)qp = af;
    }
  };

  auto phaseA = [&](int h, f32x4 (&acc)[2][4]) {  // exp + EV store + s stats
    f16* E = (f16*)EV[h & 1];
    float sl[2] = {0.f, 0.f};
#pragma unroll
    for (int nt = 0; nt < 2; ++nt)
#pragma unroll
      for (int mi = 0; mi < 2; ++mi) {
        float e0 = __expf(acc[mi][nt][0]);
        float e1 = __expf(acc[mi][nt][1]);
        float e2 = __expf(acc[mi][nt][2]);
        float e3 = __expf(acc[mi][nt][3]);
        sl[nt] += (e0 + e1) + (e2 + e3);
        *(f16x4*)&E[(16 * nt + ln) * LDP + 32 * w + 16 * mi + 4 * lg] =
            (f16x4){(f16)e0, (f16)e1, (f16)e2, (f16)e3};
        f32x4 vv = acc[mi][nt + 2];
        *(f16x4*)&E[(32 + 16 * nt + ln) * LDP + 32 * w + 16 * mi + 4 * lg] =
            (f16x4){(f16)vv[0], (f16)vv[1], (f16)vv[2], (f16)vv[3]};
      }
#pragma unroll
    for (int nt = 0; nt < 2; ++nt) {
      sl[nt] += __shfl_xor(sl[nt], 16);
      sl[nt] += __shfl_xor(sl[nt], 32);
    }
    f16* sp = (f16*)(stats + (size_t)(blk * HH + h) * STATB + 2048);
    if (lg == 0) {
      sp[ln * 4 + w] = (f16)sl[0];
      sp[(16 + ln) * 4 + w] = (f16)sl[1];
    }
  };

  auto phaseB = [&](int h) {  // barrier + t-MFMA + t store
    __syncthreads();
    const f16* E = (const f16*)EV[h & 1];
    const int tm = w >> 1, tn = w & 1;
    f32x4 tacc = Z4;
    __builtin_amdgcn_s_setprio(1);
#pragma unroll
    for (int ks = 0; ks < 4; ++ks) {
      f16x8 ea = *(const f16x8*)&E[(16 * tm + ln) * LDP + 32 * ks + 8 * lg];
      f16x8 vb = *(const f16x8*)&E[(32 + 16 * tn + ln) * LDP + 32 * ks + 8 * lg];
      tacc = MFMA(ea, vb, tacc);
    }
    __builtin_amdgcn_s_setprio(0);
    f16* tp = (f16*)(stats + (size_t)(blk * HH + h) * STATB);
#pragma unroll
    for (int r = 0; r < 4; ++r)
      tp[(16 * tm + 4 * lg + r) * 32 + 16 * tn + ln] = (f16)tacc[r];
  };

  f32x4 accA[2][4], accB[2][4], qa[2][2];
  logits(0, accA);
  phaseA(0, accA); qlog(0, qa); qfin(0, qa); logits(1, accB); phaseB(0);
  phaseA(1, accB); qlog(1, qa); qfin(1, qa); logits(2, accA); phaseB(1);
  phaseA(2, accA); qlog(2, qa); qfin(2, qa); logits(3, accB); phaseB(2);
  phaseA(3, accB); qlog(3, qa); qfin(3, qa); phaseB(3);
}

// ---------------------------------------------------------------------------
// k2: block per (b,h,d): plain sum of 256 chunk stats -> ctxN[bh][d][e] f16
// ---------------------------------------------------------------------------
__global__ __launch_bounds__(256)
void la_k2_combine(const char* __restrict__ stats, f16* __restrict__ ctxN) {
  const int gid = blockIdx.x;  // bh*32 + d
  const int bh = gid >> 5, d = gid & 31;
  const int b = bh >> 2, h = bh & 3;
  const int t = threadIdx.x, w = t >> 6, l = t & 63;
  const int c = t & 31, grp = t >> 5;
  __shared__ float redt[4][32];
  __shared__ float reds[4];

  float sg = 0.f, tc = 0.f;
  for (int i = grp; i < 256; i += 8) {
    const char* ub = stats + (size_t)((b * 256 + i) * HH + h) * STATB;
    tc += (float)((const f16*)ub)[d * 32 + c];
    f16x4 s4 = *(const f16x4*)(ub + 2048 + d * 8);
    sg += ((float)s4[0] + (float)s4[1]) + ((float)s4[2] + (float)s4[3]);
  }
  tc += __shfl_xor(tc, 32);
  sg += __shfl_xor(sg, 32);
  if (l < 32) redt[w][l] = tc;
  if (l == 0) reds[w] = sg;
  __syncthreads();
  if (t < 32) {
    float tt = (redt[0][t] + redt[1][t]) + (redt[2][t] + redt[3][t]);
    float ss = (reds[0] + reds[1]) + (reds[2] + reds[3]);
    ctxN[((size_t)bh * 32 + d) * 32 + t] = (f16)(tt / ss);
  }
}

// ---------------------------------------------------------------------------
// k2b: GT fold, written FRAGMENT-MAJOR to global (wout fp32 read direct):
//   GTF chunk h*8+mt, lane l', elem j holds GT(c = 16mt+(l'&15), d = 8(l'>>4)+j)
// ---------------------------------------------------------------------------
__global__ __launch_bounds__(256)
void la_k2b_fold(const f16* __restrict__ ctxN, const float* __restrict__ wout,
                 f16* __restrict__ GTF) {
  const int b = blockIdx.x, t = threadIdx.x;
  const int h = t >> 6, l = t & 63, lg = l >> 4, ln = l & 15;
  const f32x4 Z4 = {0.f, 0.f, 0.f, 0.f};

  const f16* cb = ctxN + (size_t)((b * HH + h) * 32) * 32;
  f16x8 bfrag[2];
#pragma unroll
  for (int nt = 0; nt < 2; ++nt)
    bfrag[nt] = *(const f16x8*)(cb + (16 * nt + ln) * 32 + 8 * lg);

  f16* gf = GTF + (size_t)b * 16384;
#pragma unroll
  for (int mt = 0; mt < 8; ++mt) {
    f16x8 af;  // wout rows c=16mt+ln, k = hid 32h+8lg+j  (fp32 direct)
#pragma unroll
    for (int j = 0; j < 8; ++j)
      af[j] = (f16)wout[(32 * h + 8 * lg + j) * 128 + 16 * mt + ln];
#pragma unroll
    for (int nt = 0; nt < 2; ++nt) {
      f32x4 acc = MFMA(af, bfrag[nt], Z4);
      // lane holds GT(c = 16mt+4lg+r, d = 16nt+ln); scatter to frag-major
#pragma unroll
      for (int r = 0; r < 4; ++r) {
        int dsub = 16 * nt + ln;
        gf[((h * 8 + mt) << 9) + (16 * (dsub >> 3) + 4 * lg + r) * 8 + (dsub & 7)] =
            (f16)acc[r];
      }
    }
  }
}

// ---------------------------------------------------------------------------
// k3: LEAN stream kernel — one wave per 32 positions (grid 4096): load 8
// prepacked Qhat fragments + 32 GTF fragments, 64 MFMA (transposed y:
// row=c, col=pos), LN (2 shuffles), f32x4 stores. No x read, no softmax,
// no LDS, no barriers.
// ---------------------------------------------------------------------------
__global__ __launch_bounds__(64)
void la_k3_out(const f16* __restrict__ Qhat, const f16* __restrict__ GTF,
               const float* __restrict__ bout, const float* __restrict__ lns,
               const float* __restrict__ lnb, float* __restrict__ out) {
  const int blk = blockIdx.x;
  const int l = threadIdx.x, lg = l >> 4, ln = l & 15;
  const int b = blk >> 10;              // 1024 blocks per batch (32 pos each)

  const f32x4 Z4 = {0.f, 0.f, 0.f, 0.f};
  const f16* gf = GTF + (size_t)b * 16384;

  // Qhat fragments for both 16-pos groups x 4 heads (independent loads)
  f16x8 af[2][4];
#pragma unroll
  for (int g = 0; g < 2; ++g)
#pragma unroll
    for (int h = 0; h < HH; ++h)
      af[g][h] = *(const f16x8*)(Qhat +
          (((size_t)(blk * 2 + g) * 4 + h) << 9) + l * 8);

  // yT[g][nc]: rows c = 16nc+4lg+r, col pos = blk*32+16g+ln
  f32x4 y[2][8];
#pragma unroll
  for (int g = 0; g < 2; ++g)
#pragma unroll
    for (int nc = 0; nc < 8; ++nc) y[g][nc] = Z4;

#pragma unroll
  for (int h = 0; h < HH; ++h) {
#pragma unroll
    for (int nc = 0; nc < 8; ++nc) {
      f16x8 gfr = *(const f16x8*)(gf + (((h * 8 + nc) << 9) + l * 8));
      y[0][nc] = MFMA(gfr, af[0][h], y[0][nc]);
      y[1][nc] = MFMA(gfr, af[1][h], y[1][nc]);
    }
  }

  // bias — vectorized f32x4 over c
#pragma unroll
  for (int nc = 0; nc < 8; ++nc) {
    f32x4 bb = *(const f32x4*)(bout + 16 * nc + 4 * lg);
    y[0][nc] += bb;
    y[1][nc] += bb;
  }

  // LayerNorm per pos (col=ln): reduce over c = (nc, lg, r): 32 in-lane + 2 shfl
#pragma unroll
  for (int g = 0; g < 2; ++g) {
    float s = 0.f;
#pragma unroll
    for (int nc = 0; nc < 8; ++nc)
      s += (y[g][nc][0] + y[g][nc][1]) + (y[g][nc][2] + y[g][nc][3]);
    s += __shfl_xor(s, 16);
    s += __shfl_xor(s, 32);
    const float mean = s * (1.f / 128.f);
    float v = 0.f;
#pragma unroll
    for (int nc = 0; nc < 8; ++nc)
#pragma unroll
      for (int r = 0; r < 4; ++r) {
        float dv = y[g][nc][r] - mean;
        v = fmaf(dv, dv, v);
      }
    v += __shfl_xor(v, 16);
    v += __shfl_xor(v, 32);
    const float inv = rsqrtf(v * (1.f / 128.f) + 1e-6f);

    float* op = out + (size_t)(blk * 32 + 16 * g + ln) * 128;
#pragma unroll
    for (int nc = 0; nc < 8; ++nc) {
      f32x4 sv = *(const f32x4*)(lns + 16 * nc + 4 * lg);
      f32x4 b2 = *(const f32x4*)(lnb + 16 * nc + 4 * lg);
      f32x4 o4;
#pragma unroll
      for (int r = 0; r < 4; ++r)
        o4[r] = (y[g][nc][r] - mean) * inv * sv[r] + b2[r];
      *(f32x4*)(op + 16 * nc + 4 * lg) = o4;
    }
  }
}

// ---------------------------------------------------------------------------
extern "C" void kernel_launch(void* const* d_in, const int* in_sizes, int n_in,
                              void* d_out, int out_size, void* d_ws, size_t ws_size,
                              hipStream_t stream) {
  const float* x = (const float*)d_in[0];
  const float* w_qkv = (const float*)d_in[1];
  const float* w_out = (const float*)d_in[2];
  const float* b_out = (const float*)d_in[3];
  const float* ln_s = (const float*)d_in[4];
  const float* ln_b = (const float*)d_in[5];
  float* out = (float*)d_out;

  char* ws = (char*)d_ws;
  char* stats = ws;                                   // 9437184 B
  f16* wkvF = (f16*)(ws + 9437184);                   // 65536 B
  f16* wqF = (f16*)(ws + 9437184 + 65536);            // 32768 B
  f16* GTF = (f16*)(ws + 9437184 + 65536 + 32768);    // 131072 B
  f16* ctxN = (f16*)(ws + 9437184 + 65536 + 32768 + 131072);  // 32768 B
  f16* Qhat = (f16*)(ws + 9437184 + 65536 + 32768 + 131072 + 32768);  // 33554432 B

  la_k0_prep<<<dim3(64), 256, 0, stream>>>(w_qkv, wkvF, wqF);
  la_k1_stats<<<dim3(NBLK), 256, 0, stream>>>(x, wkvF, wqF, stats, Qhat);
  la_k2_combine<<<dim3(512), 256, 0, stream>>>(stats, ctxN);
  la_k2b_fold<<<dim3(BB), 256, 0, stream>>>(ctxN, w_out, GTF);
  la_k3_out<<<dim3(NBLK3), 64, 0, stream>>>(Qhat, GTF, b_out, ln_s, ln_b, out);
}